// Round 1
// baseline (3247.858 us; speedup 1.0000x reference)
//
#include <hip/hip_runtime.h>

// PointNet++ SA module: FPS -> ball query -> group -> SharedMLP(3) -> maxpool
// B=8, N=8192, C_IN=64, M=1024, K=64, RADIUS=0.2, MLP=[64,64,128]

#define B_ 8
#define N_ 8192
#define M_ 1024
#define K_ 64
#define FTW 68  // 3 xyz + 64 feat + 1 pad (row = 272B, 16B aligned)

// ---------------------------------------------------------------------------
// Kernel 0: build transposed gather table ft[b][n][0..67] = {x,y,z,f0..f63,0}
// ---------------------------------------------------------------------------
__global__ __launch_bounds__(256) void build_ft_kernel(const float* __restrict__ xyz,
                                                       const float* __restrict__ feat,
                                                       float* __restrict__ ft) {
  int idx = blockIdx.x * 256 + threadIdx.x;  // over B*N*68 == 4456448 exactly
  int c = idx % FTW;
  int bn = idx / FTW;
  int n = bn & (N_ - 1);
  int b = bn >> 13;
  float v;
  if (c < 3) v = xyz[(b * 3 + c) * N_ + n];
  else if (c < 67) v = feat[(b * 64 + (c - 3)) * N_ + n];
  else v = 0.f;
  ft[idx] = v;
}

// ---------------------------------------------------------------------------
// Kernel 1: exact farthest point sampling, one block per batch.
// 1024 threads x 8 points each, all state in registers.
// Tie-break matches jnp.argmax (first occurrence) via (val desc, idx asc).
// Distances use unfused f32 mul/add in x,y,z order to match numpy/XLA.
// ---------------------------------------------------------------------------
__global__ __launch_bounds__(1024) void fps_kernel(const float* __restrict__ xyz,
                                                   float* __restrict__ nxyz) {
  __shared__ float sv[16];
  __shared__ int si[16];
  __shared__ float sc[3];
  __shared__ int scidx[M_];
  const int b = blockIdx.x;
  const int t = threadIdx.x;
  const float* xb = xyz + b * 3 * N_;
  const int base = t * 8;
  float px[8], py[8], pz[8], mind[8];
#pragma unroll
  for (int j = 0; j < 8; ++j) {
    px[j] = xb[base + j];
    py[j] = xb[N_ + base + j];
    pz[j] = xb[2 * N_ + base + j];
    mind[j] = 1e10f;
  }
  float xl = xb[0], yl = xb[N_], zl = xb[2 * N_];
  if (t == 0) scidx[0] = 0;
  for (int i = 1; i < M_; ++i) {
    float bestv = -1.f;
    int besti = 0;
#pragma unroll
    for (int j = 0; j < 8; ++j) {
      float dx = __fsub_rn(px[j], xl);
      float dy = __fsub_rn(py[j], yl);
      float dz = __fsub_rn(pz[j], zl);
      float d = __fadd_rn(__fadd_rn(__fmul_rn(dx, dx), __fmul_rn(dy, dy)), __fmul_rn(dz, dz));
      float md = fminf(mind[j], d);
      mind[j] = md;
      if (md > bestv) { bestv = md; besti = base + j; }  // ascending j -> first max kept
    }
    // wave butterfly argmax (lexicographic: larger val, then smaller idx)
#pragma unroll
    for (int off = 32; off > 0; off >>= 1) {
      float ov = __shfl_xor(bestv, off, 64);
      int oi = __shfl_xor(besti, off, 64);
      if (ov > bestv || (ov == bestv && oi < besti)) { bestv = ov; besti = oi; }
    }
    if ((t & 63) == 0) { sv[t >> 6] = bestv; si[t >> 6] = besti; }
    __syncthreads();
    float gv = sv[0];
    int gi = si[0];
#pragma unroll
    for (int w = 1; w < 16; ++w) {
      float v2 = sv[w];
      int i2 = si[w];
      if (v2 > gv || (v2 == gv && i2 < gi)) { gv = v2; gi = i2; }
    }
    // owner thread publishes winner coords (cndmask chain, no dynamic reg idx)
    if (t == (gi >> 3)) {
      const int j = gi & 7;
      float sx = px[0], sy = py[0], sz = pz[0];
#pragma unroll
      for (int q = 1; q < 8; ++q)
        if (j == q) { sx = px[q]; sy = py[q]; sz = pz[q]; }
      sc[0] = sx; sc[1] = sy; sc[2] = sz;
      scidx[i] = gi;
    }
    __syncthreads();
    xl = sc[0]; yl = sc[1]; zl = sc[2];
  }
  __syncthreads();
  if (t < M_) {
    int ci = scidx[t];
    nxyz[b * 3 * M_ + t] = xb[ci];
    nxyz[b * 3 * M_ + M_ + t] = xb[N_ + ci];
    nxyz[b * 3 * M_ + 2 * M_ + t] = xb[2 * N_ + ci];
  }
}

// ---------------------------------------------------------------------------
// Kernel 2: ball query — one wave per centroid, ordered first-K within radius.
// Replicates the reference's expanded-form distance exactly (unfused f32).
// Threshold 0.04f == f32(0.2*0.2 computed in python f64).
// ---------------------------------------------------------------------------
__global__ __launch_bounds__(256) void ballq_kernel(const float* __restrict__ xyz,
                                                    const float* __restrict__ nxyz,
                                                    int* __restrict__ nidx) {
  const int lane = threadIdx.x & 63;
  const int g = blockIdx.x * 4 + (threadIdx.x >> 6);  // 0..8191 centroid id
  const int b = g >> 10;
  const int m = g & (M_ - 1);
  const float* xb = xyz + b * 3 * N_;
  const float cx = nxyz[b * 3 * M_ + m];
  const float cy = nxyz[b * 3 * M_ + M_ + m];
  const float cz = nxyz[b * 3 * M_ + 2 * M_ + m];
  const float nc = __fadd_rn(__fadd_rn(__fmul_rn(cx, cx), __fmul_rn(cy, cy)), __fmul_rn(cz, cz));
  int cnt = 0;
  int first = 0;
  int* slot = nidx + (g << 6);
  for (int basei = 0; basei < N_ && cnt < K_; basei += 64) {
    const int n = basei + lane;
    float p_x = xb[n], p_y = xb[N_ + n], p_z = xb[2 * N_ + n];
    float pn = __fadd_rn(__fadd_rn(__fmul_rn(p_x, p_x), __fmul_rn(p_y, p_y)), __fmul_rn(p_z, p_z));
    float dt = __fadd_rn(__fadd_rn(__fmul_rn(cx, p_x), __fmul_rn(cy, p_y)), __fmul_rn(cz, p_z));
    float d2 = __fsub_rn(__fadd_rn(nc, pn), __fmul_rn(2.f, dt));
    bool inr = d2 < 0.04f;
    unsigned long long mk = __ballot(inr);
    if (cnt == 0 && mk != 0ull) first = basei + (__ffsll((long long)mk) - 1);
    int pos = cnt + (int)__popcll(mk & ((1ull << lane) - 1ull));
    if (inr && pos < K_) slot[pos] = n;
    cnt += (int)__popcll(mk);
  }
  if (cnt > K_) cnt = K_;
  if (lane >= cnt) slot[lane] = first;  // pad with first hit (0 if none)
}

// ---------------------------------------------------------------------------
// Kernel 3: fused group + SharedMLP(67->64->64->128) + max over K.
// One wave per (b,m); lane = neighbor column. Inputs + intermediates in
// registers; per-lane private LDS column (stride 65, conflict-free) bridges
// the dynamic-o store -> static-ci reload between layers. Weights are
// lane-uniform loads (compiler emits s_load). Final 128 channels butterfly
// max-reduced across the wave.
// ---------------------------------------------------------------------------
template <bool USE_FT>
__global__ __launch_bounds__(64) void mlp_kernel(
    const float* __restrict__ ft, const float* __restrict__ xyz, const float* __restrict__ feat,
    const int* __restrict__ nidx, const float* __restrict__ nxyz,
    const float* __restrict__ w0, const float* __restrict__ s0, const float* __restrict__ b0,
    const float* __restrict__ w1, const float* __restrict__ s1, const float* __restrict__ b1,
    const float* __restrict__ w2, const float* __restrict__ s2, const float* __restrict__ b2,
    float* __restrict__ out2) {
  __shared__ float ylds[64 * 65];
  const int g = blockIdx.x;
  const int b = g >> 10;
  const int m = g & (M_ - 1);
  const int lane = threadIdx.x;
  const int n = nidx[(g << 6) + lane];
  const float cx = nxyz[b * 3 * M_ + m];
  const float cy = nxyz[b * 3 * M_ + M_ + m];
  const float cz = nxyz[b * 3 * M_ + 2 * M_ + m];

  float x0[67];
  if (USE_FT) {
    const float4* row = (const float4*)(ft + (size_t)((b << 13) + n) * FTW);
    float f[FTW];
#pragma unroll
    for (int q = 0; q < 17; ++q) {
      float4 v = row[q];
      f[q * 4 + 0] = v.x; f[q * 4 + 1] = v.y; f[q * 4 + 2] = v.z; f[q * 4 + 3] = v.w;
    }
    x0[0] = f[0] - cx; x0[1] = f[1] - cy; x0[2] = f[2] - cz;
#pragma unroll
    for (int c = 3; c < 67; ++c) x0[c] = f[c];
  } else {
    const float* xb = xyz + b * 3 * N_;
    x0[0] = xb[n] - cx; x0[1] = xb[N_ + n] - cy; x0[2] = xb[2 * N_ + n] - cz;
#pragma unroll
    for (int c = 0; c < 64; ++c) x0[3 + c] = feat[((b << 6) + c) * N_ + n];
  }

  // Layer 0: 67 -> 64
  for (int o = 0; o < 64; ++o) {
    float acc = 0.f;
#pragma unroll
    for (int ci = 0; ci < 67; ++ci) acc = fmaf(w0[o * 67 + ci], x0[ci], acc);
    float v = fmaxf(fmaf(acc, s0[o], b0[o]), 0.f);
    ylds[lane * 65 + o] = v;
  }
  float x1[64];
#pragma unroll
  for (int c = 0; c < 64; ++c) x1[c] = ylds[lane * 65 + c];

  // Layer 1: 64 -> 64
  for (int o = 0; o < 64; ++o) {
    float acc = 0.f;
#pragma unroll
    for (int ci = 0; ci < 64; ++ci) acc = fmaf(w1[o * 64 + ci], x1[ci], acc);
    float v = fmaxf(fmaf(acc, s1[o], b1[o]), 0.f);
    ylds[lane * 65 + o] = v;
  }
  float x2[64];
#pragma unroll
  for (int c = 0; c < 64; ++c) x2[c] = ylds[lane * 65 + c];

  // Layer 2: 64 -> 128, fused max over the 64 neighbor columns (lanes)
  float* outbm = out2 + (size_t)(b * 128) * M_ + m;
  for (int o = 0; o < 128; ++o) {
    float acc = 0.f;
#pragma unroll
    for (int ci = 0; ci < 64; ++ci) acc = fmaf(w2[o * 64 + ci], x2[ci], acc);
    float v = fmaxf(fmaf(acc, s2[o], b2[o]), 0.f);
#pragma unroll
    for (int off = 32; off > 0; off >>= 1) v = fmaxf(v, __shfl_xor(v, off, 64));
    if (lane == (o & 63)) outbm[o * M_] = v;
  }
}

// ---------------------------------------------------------------------------
extern "C" void kernel_launch(void* const* d_in, const int* in_sizes, int n_in,
                              void* d_out, int out_size, void* d_ws, size_t ws_size,
                              hipStream_t stream) {
  const float* xyz = (const float*)d_in[0];
  const float* feat = (const float*)d_in[1];
  const float* w0 = (const float*)d_in[2];
  const float* s0 = (const float*)d_in[3];
  const float* b0 = (const float*)d_in[4];
  const float* w1 = (const float*)d_in[5];
  const float* s1 = (const float*)d_in[6];
  const float* b1 = (const float*)d_in[7];
  const float* w2 = (const float*)d_in[8];
  const float* s2 = (const float*)d_in[9];
  const float* b2 = (const float*)d_in[10];

  float* nxyz = (float*)d_out;                    // [8,3,1024]
  float* out2 = (float*)d_out + B_ * 3 * M_;      // [8,128,1024]

  const size_t nidx_bytes = (size_t)B_ * M_ * K_ * sizeof(int);        // 2 MB
  const size_t ft_bytes = (size_t)B_ * N_ * FTW * sizeof(float);       // ~17.8 MB
  int* nidx = (int*)d_ws;
  float* ft = (float*)((char*)d_ws + nidx_bytes);
  const bool use_ft = ws_size >= nidx_bytes + ft_bytes;

  if (use_ft) {
    hipLaunchKernelGGL(build_ft_kernel, dim3((B_ * N_ * FTW) / 256), dim3(256), 0, stream,
                       xyz, feat, ft);
  }
  hipLaunchKernelGGL(fps_kernel, dim3(B_), dim3(1024), 0, stream, xyz, nxyz);
  hipLaunchKernelGGL(ballq_kernel, dim3(B_ * M_ / 4), dim3(256), 0, stream, xyz, nxyz, nidx);
  if (use_ft) {
    hipLaunchKernelGGL((mlp_kernel<true>), dim3(B_ * M_), dim3(64), 0, stream,
                       ft, xyz, feat, nidx, nxyz, w0, s0, b0, w1, s1, b1, w2, s2, b2, out2);
  } else {
    hipLaunchKernelGGL((mlp_kernel<false>), dim3(B_ * M_), dim3(64), 0, stream,
                       ft, xyz, feat, nidx, nxyz, w0, s0, b0, w1, s1, b1, w2, s2, b2, out2);
  }
}

// Round 2
// 2451.238 us; speedup vs baseline: 1.3250x; 1.3250x over previous
//
#include <hip/hip_runtime.h>

// PointNet++ SA module: FPS -> ball query -> group -> SharedMLP(3) -> maxpool
// B=8, N=8192, C_IN=64, M=1024, K=64, RADIUS=0.2, MLP=[64,64,128]

#define B_ 8
#define N_ 8192
#define M_ 1024
#define K_ 64
#define FTW 68  // 3 xyz + 64 feat + 1 pad (row = 272B, 16B aligned)

// ---------------------------------------------------------------------------
// Kernel 0: build transposed gather table ft[b][n][0..67] = {x,y,z,f0..f63,0}
// ---------------------------------------------------------------------------
__global__ __launch_bounds__(256) void build_ft_kernel(const float* __restrict__ xyz,
                                                       const float* __restrict__ feat,
                                                       float* __restrict__ ft) {
  int idx = blockIdx.x * 256 + threadIdx.x;  // over B*N*68 == 4456448 exactly
  int c = idx % FTW;
  int bn = idx / FTW;
  int n = bn & (N_ - 1);
  int b = bn >> 13;
  float v;
  if (c < 3) v = xyz[(b * 3 + c) * N_ + n];
  else if (c < 67) v = feat[(b * 64 + (c - 3)) * N_ + n];
  else v = 0.f;
  ft[idx] = v;
}

// ---------------------------------------------------------------------------
// Kernel 1: exact farthest point sampling, one block (one CU) per batch.
// 512 threads (8 waves) x 16 points each, all streaming state in registers.
// Schedule: ONE barrier per iteration (parity double-buffered leader slots);
// winner coords broadcast-read from a 128KB LDS float4 table (no 2nd barrier).
// Arithmetic identical to reference: unfused f32 sub/mul/add in x,y,z order;
// argmax tie-break = first occurrence (lexicographic val desc, idx asc).
// ---------------------------------------------------------------------------
__global__ __launch_bounds__(512) void fps_kernel(const float* __restrict__ xyz,
                                                  float* __restrict__ nxyz) {
  __shared__ float4 pts4[N_];     // 128 KB point table (w unused)
  __shared__ float svv[2][8];     // parity-double-buffered wave winners
  __shared__ int sii[2][8];
  __shared__ int scidx[M_];
  const int b = blockIdx.x;
  const int t = threadIdx.x;
  const int lane = t & 63;
  const int wid = t >> 6;  // 0..7
  const float* xb = xyz + b * 3 * N_;

  // Build LDS float4 table (coalesced per-array reads).
  for (int n = t; n < N_; n += 512) {
    pts4[n] = make_float4(xb[n], xb[N_ + n], xb[2 * N_ + n], 0.f);
  }

  // Register-resident points: 16 contiguous per thread (local idx ascending).
  const int base = t * 16;
  float px[16], py[16], pz[16], mind[16];
#pragma unroll
  for (int j = 0; j < 16; ++j) {
    px[j] = xb[base + j];
    py[j] = xb[N_ + base + j];
    pz[j] = xb[2 * N_ + base + j];
    mind[j] = 1e10f;
  }
  float xl = xb[0], yl = xb[N_], zl = xb[2 * N_];
  if (t == 0) scidx[0] = 0;
  __syncthreads();

  for (int i = 1; i < M_; ++i) {
    float bestv = -1.f;
    int besti = 0;
#pragma unroll
    for (int j = 0; j < 16; ++j) {
      float dx = __fsub_rn(px[j], xl);
      float dy = __fsub_rn(py[j], yl);
      float dz = __fsub_rn(pz[j], zl);
      float d = __fadd_rn(__fadd_rn(__fmul_rn(dx, dx), __fmul_rn(dy, dy)), __fmul_rn(dz, dz));
      float md = fminf(mind[j], d);
      mind[j] = md;
      if (md > bestv) { bestv = md; besti = base + j; }  // ascending j -> first max kept
    }
    // wave butterfly argmax (lexicographic: larger val, then smaller idx)
#pragma unroll
    for (int off = 32; off > 0; off >>= 1) {
      float ov = __shfl_xor(bestv, off, 64);
      int oi = __shfl_xor(besti, off, 64);
      if (ov > bestv || (ov == bestv && oi < besti)) { bestv = ov; besti = oi; }
    }
    if (lane == 0) { svv[i & 1][wid] = bestv; sii[i & 1][wid] = besti; }
    __syncthreads();
    // all threads combine the 8 wave winners (redundant, cheap)
    float gv = svv[i & 1][0];
    int gi = sii[i & 1][0];
#pragma unroll
    for (int w = 1; w < 8; ++w) {
      float v2 = svv[i & 1][w];
      int i2 = sii[i & 1][w];
      if (v2 > gv || (v2 == gv && i2 < gi)) { gv = v2; gi = i2; }
    }
    if (t == 0) scidx[i] = gi;
    float4 c = pts4[gi];  // broadcast ds_read_b128, no conflicts
    xl = c.x; yl = c.y; zl = c.z;
    // NOTE: no second barrier. Next iteration's leader writes go to the other
    // parity buffer; all waves are within one iteration of each other.
  }
  __syncthreads();
  for (int q = t; q < M_; q += 512) {
    int ci = scidx[q];
    float4 c = pts4[ci];
    nxyz[b * 3 * M_ + q] = c.x;
    nxyz[b * 3 * M_ + M_ + q] = c.y;
    nxyz[b * 3 * M_ + 2 * M_ + q] = c.z;
  }
}

// ---------------------------------------------------------------------------
// Kernel 2: ball query — one wave per centroid, ordered first-K within radius.
// Replicates the reference's expanded-form distance exactly (unfused f32).
// Threshold 0.04f == f32(0.2*0.2 computed in python f64).
// ---------------------------------------------------------------------------
__global__ __launch_bounds__(256) void ballq_kernel(const float* __restrict__ xyz,
                                                    const float* __restrict__ nxyz,
                                                    int* __restrict__ nidx) {
  const int lane = threadIdx.x & 63;
  const int g = blockIdx.x * 4 + (threadIdx.x >> 6);  // 0..8191 centroid id
  const int b = g >> 10;
  const int m = g & (M_ - 1);
  const float* xb = xyz + b * 3 * N_;
  const float cx = nxyz[b * 3 * M_ + m];
  const float cy = nxyz[b * 3 * M_ + M_ + m];
  const float cz = nxyz[b * 3 * M_ + 2 * M_ + m];
  const float nc = __fadd_rn(__fadd_rn(__fmul_rn(cx, cx), __fmul_rn(cy, cy)), __fmul_rn(cz, cz));
  int cnt = 0;
  int first = 0;
  int* slot = nidx + (g << 6);
  for (int basei = 0; basei < N_ && cnt < K_; basei += 64) {
    const int n = basei + lane;
    float p_x = xb[n], p_y = xb[N_ + n], p_z = xb[2 * N_ + n];
    float pn = __fadd_rn(__fadd_rn(__fmul_rn(p_x, p_x), __fmul_rn(p_y, p_y)), __fmul_rn(p_z, p_z));
    float dt = __fadd_rn(__fadd_rn(__fmul_rn(cx, p_x), __fmul_rn(cy, p_y)), __fmul_rn(cz, p_z));
    float d2 = __fsub_rn(__fadd_rn(nc, pn), __fmul_rn(2.f, dt));
    bool inr = d2 < 0.04f;
    unsigned long long mk = __ballot(inr);
    if (cnt == 0 && mk != 0ull) first = basei + (__ffsll((long long)mk) - 1);
    int pos = cnt + (int)__popcll(mk & ((1ull << lane) - 1ull));
    if (inr && pos < K_) slot[pos] = n;
    cnt += (int)__popcll(mk);
  }
  if (cnt > K_) cnt = K_;
  if (lane >= cnt) slot[lane] = first;  // pad with first hit (0 if none)
}

// ---------------------------------------------------------------------------
// Kernel 3: fused group + SharedMLP(67->64->64->128) + max over K.
// One wave per (b,m); lane = neighbor column. Inputs + intermediates in
// registers; per-lane private LDS column (stride 65, conflict-free) bridges
// the dynamic-o store -> static-ci reload between layers. Weights are
// lane-uniform loads (compiler emits s_load). Final 128 channels butterfly
// max-reduced across the wave.
// ---------------------------------------------------------------------------
template <bool USE_FT>
__global__ __launch_bounds__(64) void mlp_kernel(
    const float* __restrict__ ft, const float* __restrict__ xyz, const float* __restrict__ feat,
    const int* __restrict__ nidx, const float* __restrict__ nxyz,
    const float* __restrict__ w0, const float* __restrict__ s0, const float* __restrict__ b0,
    const float* __restrict__ w1, const float* __restrict__ s1, const float* __restrict__ b1,
    const float* __restrict__ w2, const float* __restrict__ s2, const float* __restrict__ b2,
    float* __restrict__ out2) {
  __shared__ float ylds[64 * 65];
  const int g = blockIdx.x;
  const int b = g >> 10;
  const int m = g & (M_ - 1);
  const int lane = threadIdx.x;
  const int n = nidx[(g << 6) + lane];
  const float cx = nxyz[b * 3 * M_ + m];
  const float cy = nxyz[b * 3 * M_ + M_ + m];
  const float cz = nxyz[b * 3 * M_ + 2 * M_ + m];

  float x0[67];
  if (USE_FT) {
    const float4* row = (const float4*)(ft + (size_t)((b << 13) + n) * FTW);
    float f[FTW];
#pragma unroll
    for (int q = 0; q < 17; ++q) {
      float4 v = row[q];
      f[q * 4 + 0] = v.x; f[q * 4 + 1] = v.y; f[q * 4 + 2] = v.z; f[q * 4 + 3] = v.w;
    }
    x0[0] = f[0] - cx; x0[1] = f[1] - cy; x0[2] = f[2] - cz;
#pragma unroll
    for (int c = 3; c < 67; ++c) x0[c] = f[c];
  } else {
    const float* xb = xyz + b * 3 * N_;
    x0[0] = xb[n] - cx; x0[1] = xb[N_ + n] - cy; x0[2] = xb[2 * N_ + n] - cz;
#pragma unroll
    for (int c = 0; c < 64; ++c) x0[3 + c] = feat[((b << 6) + c) * N_ + n];
  }

  // Layer 0: 67 -> 64
  for (int o = 0; o < 64; ++o) {
    float acc = 0.f;
#pragma unroll
    for (int ci = 0; ci < 67; ++ci) acc = fmaf(w0[o * 67 + ci], x0[ci], acc);
    float v = fmaxf(fmaf(acc, s0[o], b0[o]), 0.f);
    ylds[lane * 65 + o] = v;
  }
  float x1[64];
#pragma unroll
  for (int c = 0; c < 64; ++c) x1[c] = ylds[lane * 65 + c];

  // Layer 1: 64 -> 64
  for (int o = 0; o < 64; ++o) {
    float acc = 0.f;
#pragma unroll
    for (int ci = 0; ci < 64; ++ci) acc = fmaf(w1[o * 64 + ci], x1[ci], acc);
    float v = fmaxf(fmaf(acc, s1[o], b1[o]), 0.f);
    ylds[lane * 65 + o] = v;
  }
  float x2[64];
#pragma unroll
  for (int c = 0; c < 64; ++c) x2[c] = ylds[lane * 65 + c];

  // Layer 2: 64 -> 128, fused max over the 64 neighbor columns (lanes)
  float* outbm = out2 + (size_t)(b * 128) * M_ + m;
  for (int o = 0; o < 128; ++o) {
    float acc = 0.f;
#pragma unroll
    for (int ci = 0; ci < 64; ++ci) acc = fmaf(w2[o * 64 + ci], x2[ci], acc);
    float v = fmaxf(fmaf(acc, s2[o], b2[o]), 0.f);
#pragma unroll
    for (int off = 32; off > 0; off >>= 1) v = fmaxf(v, __shfl_xor(v, off, 64));
    if (lane == (o & 63)) outbm[o * M_] = v;
  }
}

// ---------------------------------------------------------------------------
extern "C" void kernel_launch(void* const* d_in, const int* in_sizes, int n_in,
                              void* d_out, int out_size, void* d_ws, size_t ws_size,
                              hipStream_t stream) {
  const float* xyz = (const float*)d_in[0];
  const float* feat = (const float*)d_in[1];
  const float* w0 = (const float*)d_in[2];
  const float* s0 = (const float*)d_in[3];
  const float* b0 = (const float*)d_in[4];
  const float* w1 = (const float*)d_in[5];
  const float* s1 = (const float*)d_in[6];
  const float* b1 = (const float*)d_in[7];
  const float* w2 = (const float*)d_in[8];
  const float* s2 = (const float*)d_in[9];
  const float* b2 = (const float*)d_in[10];

  float* nxyz = (float*)d_out;                    // [8,3,1024]
  float* out2 = (float*)d_out + B_ * 3 * M_;      // [8,128,1024]

  const size_t nidx_bytes = (size_t)B_ * M_ * K_ * sizeof(int);        // 2 MB
  const size_t ft_bytes = (size_t)B_ * N_ * FTW * sizeof(float);       // ~17.8 MB
  int* nidx = (int*)d_ws;
  float* ft = (float*)((char*)d_ws + nidx_bytes);
  const bool use_ft = ws_size >= nidx_bytes + ft_bytes;

  if (use_ft) {
    hipLaunchKernelGGL(build_ft_kernel, dim3((B_ * N_ * FTW) / 256), dim3(256), 0, stream,
                       xyz, feat, ft);
  }
  hipLaunchKernelGGL(fps_kernel, dim3(B_), dim3(512), 0, stream, xyz, nxyz);
  hipLaunchKernelGGL(ballq_kernel, dim3(B_ * M_ / 4), dim3(256), 0, stream, xyz, nxyz, nidx);
  if (use_ft) {
    hipLaunchKernelGGL((mlp_kernel<true>), dim3(B_ * M_), dim3(64), 0, stream,
                       ft, xyz, feat, nidx, nxyz, w0, s0, b0, w1, s1, b1, w2, s2, b2, out2);
  } else {
    hipLaunchKernelGGL((mlp_kernel<false>), dim3(B_ * M_), dim3(64), 0, stream,
                       ft, xyz, feat, nidx, nxyz, w0, s0, b0, w1, s1, b1, w2, s2, b2, out2);
  }
}

// Round 3
// 1988.610 us; speedup vs baseline: 1.6332x; 1.2326x over previous
//
#include <hip/hip_runtime.h>

// PointNet++ SA module: FPS -> ball query -> group -> SharedMLP(3) -> maxpool
// B=8, N=8192, C_IN=64, M=1024, K=64, RADIUS=0.2, MLP=[64,64,128]

#define B_ 8
#define N_ 8192
#define M_ 1024
#define K_ 64
#define FTW 68  // 3 xyz + 64 feat + 1 pad (row = 272B, 16B aligned)

// ---------------------------------------------------------------------------
// Kernel 0: build transposed gather table ft[b][n][0..67] = {x,y,z,f0..f63,0}
// ---------------------------------------------------------------------------
__global__ __launch_bounds__(256) void build_ft_kernel(const float* __restrict__ xyz,
                                                       const float* __restrict__ feat,
                                                       float* __restrict__ ft) {
  int idx = blockIdx.x * 256 + threadIdx.x;  // over B*N*68 == 4456448 exactly
  int c = idx % FTW;
  int bn = idx / FTW;
  int n = bn & (N_ - 1);
  int b = bn >> 13;
  float v;
  if (c < 3) v = xyz[(b * 3 + c) * N_ + n];
  else if (c < 67) v = feat[(b * 64 + (c - 3)) * N_ + n];
  else v = 0.f;
  ft[idx] = v;
}

// ---------------------------------------------------------------------------
// DPP-based lexicographic (val desc, idx asc) merge with lane permutation.
// DPP permutes are VALU ops (no LDS pipe) ~8cy latency. Any full mixing
// schedule is valid for an associative lexicographic max.
// ---------------------------------------------------------------------------
template <int CTRL>
__device__ __forceinline__ void dpp_merge(float& bv, int& bi) {
  int ovb = __builtin_amdgcn_update_dpp(0, __float_as_int(bv), CTRL, 0xF, 0xF, true);
  int oib = __builtin_amdgcn_update_dpp(0, bi, CTRL, 0xF, 0xF, true);
  float ov = __int_as_float(ovb);
  if (ov > bv || (ov == bv && oib < bi)) { bv = ov; bi = oib; }
}

// ---------------------------------------------------------------------------
// Kernel 1: exact farthest point sampling, one block (one CU) per batch.
// 512 threads (8 waves) x 16 points each, streaming state in registers.
// Reduction schedule (per iteration, ONE barrier, parity double-buffered):
//   - 4 DPP merge levels in-wave -> 16-lane-row winners   (VALU pipe only)
//   - lanes 0/16/32/48 ds_write_b64 (v,i)                 -> 32 candidates
//   - barrier
//   - each lane ds_read_b64 candidate (lane&31); 4 DPP levels + 1 shfl_xor(16)
//     -> global (gv,gi) in every lane; broadcast ds_read_b128 pts4[gi].
// Arithmetic identical to reference: unfused f32 sub/mul/add in x,y,z order;
// argmax tie-break = first occurrence (lexicographic val desc, idx asc).
// ---------------------------------------------------------------------------
struct VP { float v; int i; };

__global__ __launch_bounds__(512) void fps_kernel(const float* __restrict__ xyz,
                                                  float* __restrict__ nxyz) {
  __shared__ float4 pts4[N_];     // 128 KB point table (w unused)
  __shared__ VP cand[2][32];      // parity-double-buffered row winners
  __shared__ int scidx[M_];
  const int b = blockIdx.x;
  const int t = threadIdx.x;
  const int lane = t & 63;
  const int wid = t >> 6;  // 0..7
  const float* xb = xyz + b * 3 * N_;

  // Build LDS float4 table (coalesced per-array reads).
  for (int n = t; n < N_; n += 512) {
    pts4[n] = make_float4(xb[n], xb[N_ + n], xb[2 * N_ + n], 0.f);
  }

  // Register-resident points: 16 contiguous per thread (local idx ascending).
  const int base = t * 16;
  float px[16], py[16], pz[16], mind[16];
#pragma unroll
  for (int j = 0; j < 16; ++j) {
    px[j] = xb[base + j];
    py[j] = xb[N_ + base + j];
    pz[j] = xb[2 * N_ + base + j];
    mind[j] = 1e10f;
  }
  float xl = xb[0], yl = xb[N_], zl = xb[2 * N_];
  if (t == 0) scidx[0] = 0;
  __syncthreads();

  for (int i = 1; i < M_; ++i) {
    float bestv = -1.f;
    int besti = 0;
#pragma unroll
    for (int j = 0; j < 16; ++j) {
      float dx = __fsub_rn(px[j], xl);
      float dy = __fsub_rn(py[j], yl);
      float dz = __fsub_rn(pz[j], zl);
      float d = __fadd_rn(__fadd_rn(__fmul_rn(dx, dx), __fmul_rn(dy, dy)), __fmul_rn(dz, dz));
      float md = fminf(mind[j], d);
      mind[j] = md;
      if (md > bestv) { bestv = md; besti = base + j; }  // ascending j -> first max kept
    }
    // In-wave reduce to 16-lane-row winners: 4 DPP levels, VALU pipe only.
    dpp_merge<0xB1>(bestv, besti);   // quad_perm xor1
    dpp_merge<0x4E>(bestv, besti);   // quad_perm xor2
    dpp_merge<0x141>(bestv, besti);  // row_half_mirror: merge quad pairs
    dpp_merge<0x140>(bestv, besti);  // row_mirror: merge 8-groups -> row winner
    if ((lane & 15) == 0) {
      cand[i & 1][wid * 4 + (lane >> 4)].v = bestv;
      cand[i & 1][wid * 4 + (lane >> 4)].i = besti;
    }
    __syncthreads();
    // Combine the 32 row winners: every lane loads one, DPP-reduce, xor16.
    VP c = cand[i & 1][lane & 31];
    float gv = c.v;
    int gi = c.i;
    dpp_merge<0xB1>(gv, gi);
    dpp_merge<0x4E>(gv, gi);
    dpp_merge<0x141>(gv, gi);
    dpp_merge<0x140>(gv, gi);
    {  // final cross-row merge (entries 0..15 vs 16..31)
      float ov = __shfl_xor(gv, 16, 64);
      int oi = __shfl_xor(gi, 16, 64);
      if (ov > gv || (ov == gv && oi < gi)) { gv = ov; gi = oi; }
    }
    if (t == 0) scidx[i] = gi;
    float4 cc = pts4[gi];  // broadcast ds_read_b128, conflict-free
    xl = cc.x; yl = cc.y; zl = cc.z;
    // No second barrier: next iteration's writes go to the other parity slot.
  }
  __syncthreads();
  for (int q = t; q < M_; q += 512) {
    int ci = scidx[q];
    float4 c = pts4[ci];
    nxyz[b * 3 * M_ + q] = c.x;
    nxyz[b * 3 * M_ + M_ + q] = c.y;
    nxyz[b * 3 * M_ + 2 * M_ + q] = c.z;
  }
}

// ---------------------------------------------------------------------------
// Kernel 2: ball query — one wave per centroid, ordered first-K within radius.
// Replicates the reference's expanded-form distance exactly (unfused f32).
// Threshold 0.04f == f32(0.2*0.2 computed in python f64).
// ---------------------------------------------------------------------------
__global__ __launch_bounds__(256) void ballq_kernel(const float* __restrict__ xyz,
                                                    const float* __restrict__ nxyz,
                                                    int* __restrict__ nidx) {
  const int lane = threadIdx.x & 63;
  const int g = blockIdx.x * 4 + (threadIdx.x >> 6);  // 0..8191 centroid id
  const int b = g >> 10;
  const int m = g & (M_ - 1);
  const float* xb = xyz + b * 3 * N_;
  const float cx = nxyz[b * 3 * M_ + m];
  const float cy = nxyz[b * 3 * M_ + M_ + m];
  const float cz = nxyz[b * 3 * M_ + 2 * M_ + m];
  const float nc = __fadd_rn(__fadd_rn(__fmul_rn(cx, cx), __fmul_rn(cy, cy)), __fmul_rn(cz, cz));
  int cnt = 0;
  int first = 0;
  int* slot = nidx + (g << 6);
  for (int basei = 0; basei < N_ && cnt < K_; basei += 64) {
    const int n = basei + lane;
    float p_x = xb[n], p_y = xb[N_ + n], p_z = xb[2 * N_ + n];
    float pn = __fadd_rn(__fadd_rn(__fmul_rn(p_x, p_x), __fmul_rn(p_y, p_y)), __fmul_rn(p_z, p_z));
    float dt = __fadd_rn(__fadd_rn(__fmul_rn(cx, p_x), __fmul_rn(cy, p_y)), __fmul_rn(cz, p_z));
    float d2 = __fsub_rn(__fadd_rn(nc, pn), __fmul_rn(2.f, dt));
    bool inr = d2 < 0.04f;
    unsigned long long mk = __ballot(inr);
    if (cnt == 0 && mk != 0ull) first = basei + (__ffsll((long long)mk) - 1);
    int pos = cnt + (int)__popcll(mk & ((1ull << lane) - 1ull));
    if (inr && pos < K_) slot[pos] = n;
    cnt += (int)__popcll(mk);
  }
  if (cnt > K_) cnt = K_;
  if (lane >= cnt) slot[lane] = first;  // pad with first hit (0 if none)
}

// ---------------------------------------------------------------------------
// Kernel 3: fused group + SharedMLP(67->64->64->128) + max over K.
// One wave per (b,m); lane = neighbor column. Inputs + intermediates in
// registers; per-lane private LDS column (stride 65, conflict-free) bridges
// the dynamic-o store -> static-ci reload between layers. Weights are
// lane-uniform loads (compiler emits s_load). Final 128 channels butterfly
// max-reduced across the wave.
// ---------------------------------------------------------------------------
template <bool USE_FT>
__global__ __launch_bounds__(64) void mlp_kernel(
    const float* __restrict__ ft, const float* __restrict__ xyz, const float* __restrict__ feat,
    const int* __restrict__ nidx, const float* __restrict__ nxyz,
    const float* __restrict__ w0, const float* __restrict__ s0, const float* __restrict__ b0,
    const float* __restrict__ w1, const float* __restrict__ s1, const float* __restrict__ b1,
    const float* __restrict__ w2, const float* __restrict__ s2, const float* __restrict__ b2,
    float* __restrict__ out2) {
  __shared__ float ylds[64 * 65];
  const int g = blockIdx.x;
  const int b = g >> 10;
  const int m = g & (M_ - 1);
  const int lane = threadIdx.x;
  const int n = nidx[(g << 6) + lane];
  const float cx = nxyz[b * 3 * M_ + m];
  const float cy = nxyz[b * 3 * M_ + M_ + m];
  const float cz = nxyz[b * 3 * M_ + 2 * M_ + m];

  float x0[67];
  if (USE_FT) {
    const float4* row = (const float4*)(ft + (size_t)((b << 13) + n) * FTW);
    float f[FTW];
#pragma unroll
    for (int q = 0; q < 17; ++q) {
      float4 v = row[q];
      f[q * 4 + 0] = v.x; f[q * 4 + 1] = v.y; f[q * 4 + 2] = v.z; f[q * 4 + 3] = v.w;
    }
    x0[0] = f[0] - cx; x0[1] = f[1] - cy; x0[2] = f[2] - cz;
#pragma unroll
    for (int c = 3; c < 67; ++c) x0[c] = f[c];
  } else {
    const float* xb = xyz + b * 3 * N_;
    x0[0] = xb[n] - cx; x0[1] = xb[N_ + n] - cy; x0[2] = xb[2 * N_ + n] - cz;
#pragma unroll
    for (int c = 0; c < 64; ++c) x0[3 + c] = feat[((b << 6) + c) * N_ + n];
  }

  // Layer 0: 67 -> 64
  for (int o = 0; o < 64; ++o) {
    float acc = 0.f;
#pragma unroll
    for (int ci = 0; ci < 67; ++ci) acc = fmaf(w0[o * 67 + ci], x0[ci], acc);
    float v = fmaxf(fmaf(acc, s0[o], b0[o]), 0.f);
    ylds[lane * 65 + o] = v;
  }
  float x1[64];
#pragma unroll
  for (int c = 0; c < 64; ++c) x1[c] = ylds[lane * 65 + c];

  // Layer 1: 64 -> 64
  for (int o = 0; o < 64; ++o) {
    float acc = 0.f;
#pragma unroll
    for (int ci = 0; ci < 64; ++ci) acc = fmaf(w1[o * 64 + ci], x1[ci], acc);
    float v = fmaxf(fmaf(acc, s1[o], b1[o]), 0.f);
    ylds[lane * 65 + o] = v;
  }
  float x2[64];
#pragma unroll
  for (int c = 0; c < 64; ++c) x2[c] = ylds[lane * 65 + c];

  // Layer 2: 64 -> 128, fused max over the 64 neighbor columns (lanes)
  float* outbm = out2 + (size_t)(b * 128) * M_ + m;
  for (int o = 0; o < 128; ++o) {
    float acc = 0.f;
#pragma unroll
    for (int ci = 0; ci < 64; ++ci) acc = fmaf(w2[o * 64 + ci], x2[ci], acc);
    float v = fmaxf(fmaf(acc, s2[o], b2[o]), 0.f);
#pragma unroll
    for (int off = 32; off > 0; off >>= 1) v = fmaxf(v, __shfl_xor(v, off, 64));
    if (lane == (o & 63)) outbm[o * M_] = v;
  }
}

// ---------------------------------------------------------------------------
extern "C" void kernel_launch(void* const* d_in, const int* in_sizes, int n_in,
                              void* d_out, int out_size, void* d_ws, size_t ws_size,
                              hipStream_t stream) {
  const float* xyz = (const float*)d_in[0];
  const float* feat = (const float*)d_in[1];
  const float* w0 = (const float*)d_in[2];
  const float* s0 = (const float*)d_in[3];
  const float* b0 = (const float*)d_in[4];
  const float* w1 = (const float*)d_in[5];
  const float* s1 = (const float*)d_in[6];
  const float* b1 = (const float*)d_in[7];
  const float* w2 = (const float*)d_in[8];
  const float* s2 = (const float*)d_in[9];
  const float* b2 = (const float*)d_in[10];

  float* nxyz = (float*)d_out;                    // [8,3,1024]
  float* out2 = (float*)d_out + B_ * 3 * M_;      // [8,128,1024]

  const size_t nidx_bytes = (size_t)B_ * M_ * K_ * sizeof(int);        // 2 MB
  const size_t ft_bytes = (size_t)B_ * N_ * FTW * sizeof(float);       // ~17.8 MB
  int* nidx = (int*)d_ws;
  float* ft = (float*)((char*)d_ws + nidx_bytes);
  const bool use_ft = ws_size >= nidx_bytes + ft_bytes;

  if (use_ft) {
    hipLaunchKernelGGL(build_ft_kernel, dim3((B_ * N_ * FTW) / 256), dim3(256), 0, stream,
                       xyz, feat, ft);
  }
  hipLaunchKernelGGL(fps_kernel, dim3(B_), dim3(512), 0, stream, xyz, nxyz);
  hipLaunchKernelGGL(ballq_kernel, dim3(B_ * M_ / 4), dim3(256), 0, stream, xyz, nxyz, nidx);
  if (use_ft) {
    hipLaunchKernelGGL((mlp_kernel<true>), dim3(B_ * M_), dim3(64), 0, stream,
                       ft, xyz, feat, nidx, nxyz, w0, s0, b0, w1, s1, b1, w2, s2, b2, out2);
  } else {
    hipLaunchKernelGGL((mlp_kernel<false>), dim3(B_ * M_), dim3(64), 0, stream,
                       ft, xyz, feat, nidx, nxyz, w0, s0, b0, w1, s1, b1, w2, s2, b2, out2);
  }
}

// Round 4
// 1582.921 us; speedup vs baseline: 2.0518x; 1.2563x over previous
//
#include <hip/hip_runtime.h>

// PointNet++ SA module: FPS -> ball query -> group -> SharedMLP(3) -> maxpool
// B=8, N=8192, C_IN=64, M=1024, K=64, RADIUS=0.2, MLP=[64,64,128]

#define B_ 8
#define N_ 8192
#define M_ 1024
#define K_ 64
#define FTW 68  // 3 xyz + 64 feat + 1 pad (row = 272B, 16B aligned)

// ---------------------------------------------------------------------------
// u64-key lexicographic merge via DPP (VALU pipe, no LDS).
// key = (f32bits(val) << 32) | ~idx ; distances >= 0 so f32 bits order as u32.
// max(key) == (val desc, idx asc) — associative, any mixing schedule valid.
// ---------------------------------------------------------------------------
template <int CTRL>
__device__ __forceinline__ unsigned long long dpp_key(unsigned long long k) {
  int lo = __builtin_amdgcn_update_dpp(0, (int)(unsigned int)k, CTRL, 0xF, 0xF, true);
  int hi = __builtin_amdgcn_update_dpp(0, (int)(unsigned int)(k >> 32), CTRL, 0xF, 0xF, true);
  unsigned long long o = ((unsigned long long)(unsigned int)hi << 32) | (unsigned int)lo;
  return o > k ? o : k;
}

// ---------------------------------------------------------------------------
// Kernel 1 (fused): blocks 0..7 = exact FPS (one CU per batch);
//                   blocks 8..  = build ft[b][n][0..67] = {x,y,z,f0..f63,0}.
// FPS: 256 threads (4 waves, 1/SIMD) x 32 points each, state in registers.
// Per iteration, ONE barrier (parity double-buffered candidates):
//   - in-loop: exact unfused f32 distances, strict-> first-occurrence argmax
//     tracked as (bestv, local j via inline-const cndmask)
//   - 4 DPP levels on u64 keys -> 16-lane-row winners (4 rows x 4 waves = 16)
//   - leaders ds_write_b64 key; barrier
//   - every lane reads cand[lane&15], 4 DPP levels -> global key -> gi
//   - broadcast ds_read_b128 pts4[gi] for next centroid coords.
// ---------------------------------------------------------------------------
__global__ __launch_bounds__(256) void fps_ft_kernel(const float* __restrict__ xyz,
                                                     const float* __restrict__ feat,
                                                     float* __restrict__ ft,
                                                     float* __restrict__ nxyz) {
  if (blockIdx.x >= 8) {
    // ---- build_ft path (no LDS use, no barriers) ----
    const int nb = gridDim.x - 8;
    const int total = B_ * N_ * FTW;
    for (int idx = (blockIdx.x - 8) * 256 + threadIdx.x; idx < total; idx += nb * 256) {
      int c = idx % FTW;
      int bn = idx / FTW;
      int n = bn & (N_ - 1);
      int b = bn >> 13;
      float v;
      if (c < 3) v = xyz[(b * 3 + c) * N_ + n];
      else if (c < 67) v = feat[(b * 64 + (c - 3)) * N_ + n];
      else v = 0.f;
      ft[idx] = v;
    }
    return;
  }

  // ---- FPS path ----
  __shared__ float4 pts4[N_];                    // 128 KB point table (w unused)
  __shared__ unsigned long long cand[2][16];     // parity-buffered row-winner keys
  __shared__ int scidx[M_];
  const int b = blockIdx.x;
  const int t = threadIdx.x;
  const int lane = t & 63;
  const int wid = t >> 6;  // 0..3
  const float* xb = xyz + b * 3 * N_;

  for (int n = t; n < N_; n += 256) {
    pts4[n] = make_float4(xb[n], xb[N_ + n], xb[2 * N_ + n], 0.f);
  }

  const int base = t * 32;
  float px[32], py[32], pz[32], mind[32];
#pragma unroll
  for (int j = 0; j < 32; ++j) {
    px[j] = xb[base + j];
    py[j] = xb[N_ + base + j];
    pz[j] = xb[2 * N_ + base + j];
    mind[j] = 1e10f;
  }
  float xl = xb[0], yl = xb[N_], zl = xb[2 * N_];
  if (t == 0) scidx[0] = 0;
  __syncthreads();

  for (int i = 1; i < M_; ++i) {
    float bestv = -1.f;
    int bl = 0;  // local index 0..31 (inline-const cndmask)
#pragma unroll
    for (int j = 0; j < 32; ++j) {
      float dx = __fsub_rn(px[j], xl);
      float dy = __fsub_rn(py[j], yl);
      float dz = __fsub_rn(pz[j], zl);
      float d = __fadd_rn(__fadd_rn(__fmul_rn(dx, dx), __fmul_rn(dy, dy)), __fmul_rn(dz, dz));
      float md = fminf(mind[j], d);
      mind[j] = md;
      if (md > bestv) { bestv = md; bl = j; }  // ascending j -> first max kept
    }
    unsigned long long key =
        ((unsigned long long)__float_as_uint(bestv) << 32) | (unsigned int)(~(base + bl));
    // in-wave reduce to 16-lane-row winners: 4 DPP levels, VALU pipe only
    key = dpp_key<0xB1>(key);   // quad_perm [1,0,3,2]
    key = dpp_key<0x4E>(key);   // quad_perm [2,3,0,1]
    key = dpp_key<0x141>(key);  // row_half_mirror
    key = dpp_key<0x140>(key);  // row_mirror -> 16-lane-row winner
    if ((lane & 15) == 0) cand[i & 1][wid * 4 + (lane >> 4)] = key;
    __syncthreads();
    // combine 16 row winners: broadcast read, 4 DPP levels within each 16-row
    unsigned long long gk = cand[i & 1][lane & 15];
    gk = dpp_key<0xB1>(gk);
    gk = dpp_key<0x4E>(gk);
    gk = dpp_key<0x141>(gk);
    gk = dpp_key<0x140>(gk);
    const int gi = (int)(~(unsigned int)gk);
    if (t == 0) scidx[i] = gi;
    float4 cc = pts4[gi];  // broadcast ds_read_b128, conflict-free
    xl = cc.x; yl = cc.y; zl = cc.z;
    // no second barrier: next iteration's leader writes go to the other parity
  }
  __syncthreads();
  for (int q = t; q < M_; q += 256) {
    int ci = scidx[q];
    float4 c = pts4[ci];
    nxyz[b * 3 * M_ + q] = c.x;
    nxyz[b * 3 * M_ + M_ + q] = c.y;
    nxyz[b * 3 * M_ + 2 * M_ + q] = c.z;
  }
}

// ---------------------------------------------------------------------------
// Kernel 2: ball query — one wave per centroid, ordered first-K within radius.
// Replicates the reference's expanded-form distance exactly (unfused f32).
// Threshold 0.04f == f32(0.2*0.2 computed in python f64).
// ---------------------------------------------------------------------------
__global__ __launch_bounds__(256) void ballq_kernel(const float* __restrict__ xyz,
                                                    const float* __restrict__ nxyz,
                                                    int* __restrict__ nidx) {
  const int lane = threadIdx.x & 63;
  const int g = blockIdx.x * 4 + (threadIdx.x >> 6);  // 0..8191 centroid id
  const int b = g >> 10;
  const int m = g & (M_ - 1);
  const float* xb = xyz + b * 3 * N_;
  const float cx = nxyz[b * 3 * M_ + m];
  const float cy = nxyz[b * 3 * M_ + M_ + m];
  const float cz = nxyz[b * 3 * M_ + 2 * M_ + m];
  const float nc = __fadd_rn(__fadd_rn(__fmul_rn(cx, cx), __fmul_rn(cy, cy)), __fmul_rn(cz, cz));
  int cnt = 0;
  int first = 0;
  int* slot = nidx + (g << 6);
  for (int basei = 0; basei < N_ && cnt < K_; basei += 64) {
    const int n = basei + lane;
    float p_x = xb[n], p_y = xb[N_ + n], p_z = xb[2 * N_ + n];
    float pn = __fadd_rn(__fadd_rn(__fmul_rn(p_x, p_x), __fmul_rn(p_y, p_y)), __fmul_rn(p_z, p_z));
    float dt = __fadd_rn(__fadd_rn(__fmul_rn(cx, p_x), __fmul_rn(cy, p_y)), __fmul_rn(cz, p_z));
    float d2 = __fsub_rn(__fadd_rn(nc, pn), __fmul_rn(2.f, dt));
    bool inr = d2 < 0.04f;
    unsigned long long mk = __ballot(inr);
    if (cnt == 0 && mk != 0ull) first = basei + (__ffsll((long long)mk) - 1);
    int pos = cnt + (int)__popcll(mk & ((1ull << lane) - 1ull));
    if (inr && pos < K_) slot[pos] = n;
    cnt += (int)__popcll(mk);
  }
  if (cnt > K_) cnt = K_;
  if (lane >= cnt) slot[lane] = first;  // pad with first hit (0 if none)
}

// ---------------------------------------------------------------------------
// Kernel 3: fused group + SharedMLP(67->64->64->128) + max over K.
// One wave per (b,m); lane = neighbor column. Inputs + intermediates in
// registers; per-lane private LDS column (stride 65, conflict-free) bridges
// the dynamic-o store -> static-ci reload between layers. Weights are
// lane-uniform loads (compiler emits s_load). Final 128 channels butterfly
// max-reduced across the wave.
// ---------------------------------------------------------------------------
template <bool USE_FT>
__global__ __launch_bounds__(64) void mlp_kernel(
    const float* __restrict__ ft, const float* __restrict__ xyz, const float* __restrict__ feat,
    const int* __restrict__ nidx, const float* __restrict__ nxyz,
    const float* __restrict__ w0, const float* __restrict__ s0, const float* __restrict__ b0,
    const float* __restrict__ w1, const float* __restrict__ s1, const float* __restrict__ b1,
    const float* __restrict__ w2, const float* __restrict__ s2, const float* __restrict__ b2,
    float* __restrict__ out2) {
  __shared__ float ylds[64 * 65];
  const int g = blockIdx.x;
  const int b = g >> 10;
  const int m = g & (M_ - 1);
  const int lane = threadIdx.x;
  const int n = nidx[(g << 6) + lane];
  const float cx = nxyz[b * 3 * M_ + m];
  const float cy = nxyz[b * 3 * M_ + M_ + m];
  const float cz = nxyz[b * 3 * M_ + 2 * M_ + m];

  float x0[67];
  if (USE_FT) {
    const float4* row = (const float4*)(ft + (size_t)((b << 13) + n) * FTW);
    float f[FTW];
#pragma unroll
    for (int q = 0; q < 17; ++q) {
      float4 v = row[q];
      f[q * 4 + 0] = v.x; f[q * 4 + 1] = v.y; f[q * 4 + 2] = v.z; f[q * 4 + 3] = v.w;
    }
    x0[0] = f[0] - cx; x0[1] = f[1] - cy; x0[2] = f[2] - cz;
#pragma unroll
    for (int c = 3; c < 67; ++c) x0[c] = f[c];
  } else {
    const float* xb = xyz + b * 3 * N_;
    x0[0] = xb[n] - cx; x0[1] = xb[N_ + n] - cy; x0[2] = xb[2 * N_ + n] - cz;
#pragma unroll
    for (int c = 0; c < 64; ++c) x0[3 + c] = feat[((b << 6) + c) * N_ + n];
  }

  // Layer 0: 67 -> 64
  for (int o = 0; o < 64; ++o) {
    float acc = 0.f;
#pragma unroll
    for (int ci = 0; ci < 67; ++ci) acc = fmaf(w0[o * 67 + ci], x0[ci], acc);
    float v = fmaxf(fmaf(acc, s0[o], b0[o]), 0.f);
    ylds[lane * 65 + o] = v;
  }
  float x1[64];
#pragma unroll
  for (int c = 0; c < 64; ++c) x1[c] = ylds[lane * 65 + c];

  // Layer 1: 64 -> 64
  for (int o = 0; o < 64; ++o) {
    float acc = 0.f;
#pragma unroll
    for (int ci = 0; ci < 64; ++ci) acc = fmaf(w1[o * 64 + ci], x1[ci], acc);
    float v = fmaxf(fmaf(acc, s1[o], b1[o]), 0.f);
    ylds[lane * 65 + o] = v;
  }
  float x2[64];
#pragma unroll
  for (int c = 0; c < 64; ++c) x2[c] = ylds[lane * 65 + c];

  // Layer 2: 64 -> 128, fused max over the 64 neighbor columns (lanes)
  float* outbm = out2 + (size_t)(b * 128) * M_ + m;
  for (int o = 0; o < 128; ++o) {
    float acc = 0.f;
#pragma unroll
    for (int ci = 0; ci < 64; ++ci) acc = fmaf(w2[o * 64 + ci], x2[ci], acc);
    float v = fmaxf(fmaf(acc, s2[o], b2[o]), 0.f);
#pragma unroll
    for (int off = 32; off > 0; off >>= 1) v = fmaxf(v, __shfl_xor(v, off, 64));
    if (lane == (o & 63)) outbm[o * M_] = v;
  }
}

// ---------------------------------------------------------------------------
extern "C" void kernel_launch(void* const* d_in, const int* in_sizes, int n_in,
                              void* d_out, int out_size, void* d_ws, size_t ws_size,
                              hipStream_t stream) {
  const float* xyz = (const float*)d_in[0];
  const float* feat = (const float*)d_in[1];
  const float* w0 = (const float*)d_in[2];
  const float* s0 = (const float*)d_in[3];
  const float* b0 = (const float*)d_in[4];
  const float* w1 = (const float*)d_in[5];
  const float* s1 = (const float*)d_in[6];
  const float* b1 = (const float*)d_in[7];
  const float* w2 = (const float*)d_in[8];
  const float* s2 = (const float*)d_in[9];
  const float* b2 = (const float*)d_in[10];

  float* nxyz = (float*)d_out;                    // [8,3,1024]
  float* out2 = (float*)d_out + B_ * 3 * M_;      // [8,128,1024]

  const size_t nidx_bytes = (size_t)B_ * M_ * K_ * sizeof(int);        // 2 MB
  const size_t ft_bytes = (size_t)B_ * N_ * FTW * sizeof(float);       // ~17.8 MB
  int* nidx = (int*)d_ws;
  float* ft = (float*)((char*)d_ws + nidx_bytes);
  const bool use_ft = ws_size >= nidx_bytes + ft_bytes;

  // FPS (blocks 0-7) fused with ft-table build (blocks 8-63) — independent work.
  hipLaunchKernelGGL(fps_ft_kernel, dim3(use_ft ? 64 : 8), dim3(256), 0, stream,
                     xyz, feat, ft, nxyz);
  hipLaunchKernelGGL(ballq_kernel, dim3(B_ * M_ / 4), dim3(256), 0, stream, xyz, nxyz, nidx);
  if (use_ft) {
    hipLaunchKernelGGL((mlp_kernel<true>), dim3(B_ * M_), dim3(64), 0, stream,
                       ft, xyz, feat, nidx, nxyz, w0, s0, b0, w1, s1, b1, w2, s2, b2, out2);
  } else {
    hipLaunchKernelGGL((mlp_kernel<false>), dim3(B_ * M_), dim3(64), 0, stream,
                       ft, xyz, feat, nidx, nxyz, w0, s0, b0, w1, s1, b1, w2, s2, b2, out2);
  }
}

// Round 5
// 1398.439 us; speedup vs baseline: 2.3225x; 1.1319x over previous
//
#include <hip/hip_runtime.h>

// PointNet++ SA module: FPS -> ball query -> group -> SharedMLP(3) -> maxpool
// B=8, N=8192, C_IN=64, M=1024, K=64, RADIUS=0.2, MLP=[64,64,128]

#define B_ 8
#define N_ 8192
#define M_ 1024
#define K_ 64
#define FTW 68  // 3 xyz + 64 feat + 1 pad (row = 272B, 16B aligned)

typedef float vf2 __attribute__((ext_vector_type(2)));

// ---------------------------------------------------------------------------
// u64-key lexicographic merge via DPP (VALU pipe, no LDS).
// key = (f32bits(val) << 32) | ~idx ; distances >= 0 so f32 bits order as u32.
// max(key) == (val desc, idx asc) — associative, any mixing schedule valid.
// ---------------------------------------------------------------------------
template <int CTRL>
__device__ __forceinline__ unsigned long long dpp_key(unsigned long long k) {
  int lo = __builtin_amdgcn_update_dpp(0, (int)(unsigned int)k, CTRL, 0xF, 0xF, true);
  int hi = __builtin_amdgcn_update_dpp(0, (int)(unsigned int)(k >> 32), CTRL, 0xF, 0xF, true);
  unsigned long long o = ((unsigned long long)(unsigned int)hi << 32) | (unsigned int)lo;
  return o > k ? o : k;
}

// ---------------------------------------------------------------------------
// Kernel 1 (fused): blocks 0..7 = exact FPS (one CU per batch);
//                   blocks 8..  = build ft[b][n][0..67] = {x,y,z,f0..f63,0}.
// FPS: 256 threads (4 waves, 1/SIMD) x 32 points each (16 float2 pairs).
// Distance loop on packed float2 (v_pk_*_f32 capable), contract(off) keeps
// unfused mul/add rounding == reference. Selection scan is scalar in
// ascending point order -> first-occurrence argmax preserved exactly.
// ---------------------------------------------------------------------------
__global__ __launch_bounds__(256) void fps_ft_kernel(const float* __restrict__ xyz,
                                                     const float* __restrict__ feat,
                                                     float* __restrict__ ft,
                                                     float* __restrict__ nxyz) {
#pragma clang fp contract(off)
  if (blockIdx.x >= 8) {
    // ---- build_ft path (no LDS use, no barriers) ----
    const int nb = gridDim.x - 8;
    const int total = B_ * N_ * FTW;
    for (int idx = (blockIdx.x - 8) * 256 + threadIdx.x; idx < total; idx += nb * 256) {
      int c = idx % FTW;
      int bn = idx / FTW;
      int n = bn & (N_ - 1);
      int b = bn >> 13;
      float v;
      if (c < 3) v = xyz[(b * 3 + c) * N_ + n];
      else if (c < 67) v = feat[(b * 64 + (c - 3)) * N_ + n];
      else v = 0.f;
      ft[idx] = v;
    }
    return;
  }

  // ---- FPS path ----
  __shared__ float4 pts4[N_];                    // 128 KB point table (w unused)
  __shared__ unsigned long long cand[2][16];     // parity-buffered row-winner keys
  __shared__ int scidx[M_];
  const int b = blockIdx.x;
  const int t = threadIdx.x;
  const int lane = t & 63;
  const int wid = t >> 6;  // 0..3
  const float* xb = xyz + b * 3 * N_;

  for (int n = t; n < N_; n += 256) {
    pts4[n] = make_float4(xb[n], xb[N_ + n], xb[2 * N_ + n], 0.f);
  }

  const int base = t * 32;  // 32 points = 16 float2 pairs, 128B aligned
  const vf2* xv = (const vf2*)(xb + base);
  const vf2* yv = (const vf2*)(xb + N_ + base);
  const vf2* zv = (const vf2*)(xb + 2 * N_ + base);
  vf2 px2[16], py2[16], pz2[16], mind2[16];
#pragma unroll
  for (int j = 0; j < 16; ++j) {
    px2[j] = xv[j];
    py2[j] = yv[j];
    pz2[j] = zv[j];
    mind2[j] = vf2{1e10f, 1e10f};
  }
  float xl = xb[0], yl = xb[N_], zl = xb[2 * N_];
  if (t == 0) scidx[0] = 0;
  __syncthreads();

  for (int i = 1; i < M_; ++i) {
    const vf2 xl2 = vf2{xl, xl}, yl2 = vf2{yl, yl}, zl2 = vf2{zl, zl};
    float bestv = -1.f;
    int bl = 0;  // local point index 0..31
#pragma unroll
    for (int j = 0; j < 16; ++j) {
      vf2 dx = px2[j] - xl2;
      vf2 dy = py2[j] - yl2;
      vf2 dz = pz2[j] - zl2;
      vf2 d = (dx * dx + dy * dy) + dz * dz;  // contract(off): unfused mul/add
      vf2 md;
      md.x = fminf(mind2[j].x, d.x);
      md.y = fminf(mind2[j].y, d.y);
      mind2[j] = md;
      if (md.x > bestv) { bestv = md.x; bl = 2 * j; }      // ascending order ->
      if (md.y > bestv) { bestv = md.y; bl = 2 * j + 1; }  // first max kept
    }
    unsigned long long key =
        ((unsigned long long)__float_as_uint(bestv) << 32) | (unsigned int)(~(base + bl));
    // in-wave reduce to 16-lane-row winners: 4 DPP levels, VALU pipe only
    key = dpp_key<0xB1>(key);   // quad_perm [1,0,3,2]
    key = dpp_key<0x4E>(key);   // quad_perm [2,3,0,1]
    key = dpp_key<0x141>(key);  // row_half_mirror
    key = dpp_key<0x140>(key);  // row_mirror -> 16-lane-row winner
    if ((lane & 15) == 0) cand[i & 1][wid * 4 + (lane >> 4)] = key;
    __syncthreads();
    // combine 16 row winners: broadcast read, 4 DPP levels within each 16-row
    unsigned long long gk = cand[i & 1][lane & 15];
    gk = dpp_key<0xB1>(gk);
    gk = dpp_key<0x4E>(gk);
    gk = dpp_key<0x141>(gk);
    gk = dpp_key<0x140>(gk);
    const int gi = (int)(~(unsigned int)gk);
    if (t == 0) scidx[i] = gi;
    float4 cc = pts4[gi];  // broadcast ds_read_b128, conflict-free
    xl = cc.x; yl = cc.y; zl = cc.z;
    // no second barrier: next iteration's leader writes go to the other parity
  }
  __syncthreads();
  for (int q = t; q < M_; q += 256) {
    int ci = scidx[q];
    float4 c = pts4[ci];
    nxyz[b * 3 * M_ + q] = c.x;
    nxyz[b * 3 * M_ + M_ + q] = c.y;
    nxyz[b * 3 * M_ + 2 * M_ + q] = c.z;
  }
}

// ---------------------------------------------------------------------------
// Kernel 2: ball query — one wave per centroid, ordered first-K within radius.
// Replicates the reference's expanded-form distance exactly (unfused f32).
// Threshold 0.04f == f32(0.2*0.2 computed in python f64).
// ---------------------------------------------------------------------------
__global__ __launch_bounds__(256) void ballq_kernel(const float* __restrict__ xyz,
                                                    const float* __restrict__ nxyz,
                                                    int* __restrict__ nidx) {
  const int lane = threadIdx.x & 63;
  const int g = blockIdx.x * 4 + (threadIdx.x >> 6);  // 0..8191 centroid id
  const int b = g >> 10;
  const int m = g & (M_ - 1);
  const float* xb = xyz + b * 3 * N_;
  const float cx = nxyz[b * 3 * M_ + m];
  const float cy = nxyz[b * 3 * M_ + M_ + m];
  const float cz = nxyz[b * 3 * M_ + 2 * M_ + m];
  const float nc = __fadd_rn(__fadd_rn(__fmul_rn(cx, cx), __fmul_rn(cy, cy)), __fmul_rn(cz, cz));
  int cnt = 0;
  int first = 0;
  int* slot = nidx + (g << 6);
  for (int basei = 0; basei < N_ && cnt < K_; basei += 64) {
    const int n = basei + lane;
    float p_x = xb[n], p_y = xb[N_ + n], p_z = xb[2 * N_ + n];
    float pn = __fadd_rn(__fadd_rn(__fmul_rn(p_x, p_x), __fmul_rn(p_y, p_y)), __fmul_rn(p_z, p_z));
    float dt = __fadd_rn(__fadd_rn(__fmul_rn(cx, p_x), __fmul_rn(cy, p_y)), __fmul_rn(cz, p_z));
    float d2 = __fsub_rn(__fadd_rn(nc, pn), __fmul_rn(2.f, dt));
    bool inr = d2 < 0.04f;
    unsigned long long mk = __ballot(inr);
    if (cnt == 0 && mk != 0ull) first = basei + (__ffsll((long long)mk) - 1);
    int pos = cnt + (int)__popcll(mk & ((1ull << lane) - 1ull));
    if (inr && pos < K_) slot[pos] = n;
    cnt += (int)__popcll(mk);
  }
  if (cnt > K_) cnt = K_;
  if (lane >= cnt) slot[lane] = first;  // pad with first hit (0 if none)
}

// ---------------------------------------------------------------------------
// Kernel 3: fused group + SharedMLP(67->64->64->128) + max over K.
// One wave per (b,m); lane = neighbor column. 4-way output unroll gives 4
// independent fmaf chains (latency 4cy / issue 2cy needs >=2; 4 covers
// scheduling gaps at ~2 waves/SIMD residency). LDS column (stride 65,
// conflict-free) bridges dynamic-o stores -> static-ci reloads. Layer-2
// butterflies run 4-wide interleaved.
// ---------------------------------------------------------------------------
template <bool USE_FT>
__global__ __launch_bounds__(64) void mlp_kernel(
    const float* __restrict__ ft, const float* __restrict__ xyz, const float* __restrict__ feat,
    const int* __restrict__ nidx, const float* __restrict__ nxyz,
    const float* __restrict__ w0, const float* __restrict__ s0, const float* __restrict__ b0,
    const float* __restrict__ w1, const float* __restrict__ s1, const float* __restrict__ b1,
    const float* __restrict__ w2, const float* __restrict__ s2, const float* __restrict__ b2,
    float* __restrict__ out2) {
  __shared__ float ylds[64 * 65];
  const int g = blockIdx.x;
  const int b = g >> 10;
  const int m = g & (M_ - 1);
  const int lane = threadIdx.x;
  const int n = nidx[(g << 6) + lane];
  const float cx = nxyz[b * 3 * M_ + m];
  const float cy = nxyz[b * 3 * M_ + M_ + m];
  const float cz = nxyz[b * 3 * M_ + 2 * M_ + m];

  float x0[67];
  if (USE_FT) {
    const float4* row = (const float4*)(ft + (size_t)((b << 13) + n) * FTW);
    float f[FTW];
#pragma unroll
    for (int q = 0; q < 17; ++q) {
      float4 v = row[q];
      f[q * 4 + 0] = v.x; f[q * 4 + 1] = v.y; f[q * 4 + 2] = v.z; f[q * 4 + 3] = v.w;
    }
    x0[0] = f[0] - cx; x0[1] = f[1] - cy; x0[2] = f[2] - cz;
#pragma unroll
    for (int c = 3; c < 67; ++c) x0[c] = f[c];
  } else {
    const float* xb = xyz + b * 3 * N_;
    x0[0] = xb[n] - cx; x0[1] = xb[N_ + n] - cy; x0[2] = xb[2 * N_ + n] - cz;
#pragma unroll
    for (int c = 0; c < 64; ++c) x0[3 + c] = feat[((b << 6) + c) * N_ + n];
  }

  // Layer 0: 67 -> 64 (4 outputs in flight)
  for (int o = 0; o < 64; o += 4) {
    const float* wr = w0 + o * 67;
    float a0 = 0.f, a1 = 0.f, a2 = 0.f, a3 = 0.f;
#pragma unroll
    for (int ci = 0; ci < 67; ++ci) {
      float xvv = x0[ci];
      a0 = fmaf(wr[ci], xvv, a0);
      a1 = fmaf(wr[67 + ci], xvv, a1);
      a2 = fmaf(wr[134 + ci], xvv, a2);
      a3 = fmaf(wr[201 + ci], xvv, a3);
    }
    ylds[lane * 65 + o + 0] = fmaxf(fmaf(a0, s0[o + 0], b0[o + 0]), 0.f);
    ylds[lane * 65 + o + 1] = fmaxf(fmaf(a1, s0[o + 1], b0[o + 1]), 0.f);
    ylds[lane * 65 + o + 2] = fmaxf(fmaf(a2, s0[o + 2], b0[o + 2]), 0.f);
    ylds[lane * 65 + o + 3] = fmaxf(fmaf(a3, s0[o + 3], b0[o + 3]), 0.f);
  }
  float x1[64];
#pragma unroll
  for (int c = 0; c < 64; ++c) x1[c] = ylds[lane * 65 + c];

  // Layer 1: 64 -> 64 (4 outputs in flight)
  for (int o = 0; o < 64; o += 4) {
    const float* wr = w1 + o * 64;
    float a0 = 0.f, a1 = 0.f, a2 = 0.f, a3 = 0.f;
#pragma unroll
    for (int ci = 0; ci < 64; ++ci) {
      float xvv = x1[ci];
      a0 = fmaf(wr[ci], xvv, a0);
      a1 = fmaf(wr[64 + ci], xvv, a1);
      a2 = fmaf(wr[128 + ci], xvv, a2);
      a3 = fmaf(wr[192 + ci], xvv, a3);
    }
    ylds[lane * 65 + o + 0] = fmaxf(fmaf(a0, s1[o + 0], b1[o + 0]), 0.f);
    ylds[lane * 65 + o + 1] = fmaxf(fmaf(a1, s1[o + 1], b1[o + 1]), 0.f);
    ylds[lane * 65 + o + 2] = fmaxf(fmaf(a2, s1[o + 2], b1[o + 2]), 0.f);
    ylds[lane * 65 + o + 3] = fmaxf(fmaf(a3, s1[o + 3], b1[o + 3]), 0.f);
  }
  float x2[64];
#pragma unroll
  for (int c = 0; c < 64; ++c) x2[c] = ylds[lane * 65 + c];

  // Layer 2: 64 -> 128, fused max over K (4 interleaved butterflies)
  float* outbm = out2 + (size_t)(b * 128) * M_ + m;
  for (int o = 0; o < 128; o += 4) {
    const float* wr = w2 + o * 64;
    float a0 = 0.f, a1 = 0.f, a2 = 0.f, a3 = 0.f;
#pragma unroll
    for (int ci = 0; ci < 64; ++ci) {
      float xvv = x2[ci];
      a0 = fmaf(wr[ci], xvv, a0);
      a1 = fmaf(wr[64 + ci], xvv, a1);
      a2 = fmaf(wr[128 + ci], xvv, a2);
      a3 = fmaf(wr[192 + ci], xvv, a3);
    }
    float v0 = fmaxf(fmaf(a0, s2[o + 0], b2[o + 0]), 0.f);
    float v1 = fmaxf(fmaf(a1, s2[o + 1], b2[o + 1]), 0.f);
    float v2 = fmaxf(fmaf(a2, s2[o + 2], b2[o + 2]), 0.f);
    float v3 = fmaxf(fmaf(a3, s2[o + 3], b2[o + 3]), 0.f);
#pragma unroll
    for (int off = 32; off > 0; off >>= 1) {
      v0 = fmaxf(v0, __shfl_xor(v0, off, 64));
      v1 = fmaxf(v1, __shfl_xor(v1, off, 64));
      v2 = fmaxf(v2, __shfl_xor(v2, off, 64));
      v3 = fmaxf(v3, __shfl_xor(v3, off, 64));
    }
    if (lane == ((o + 0) & 63)) outbm[(o + 0) * M_] = v0;
    if (lane == ((o + 1) & 63)) outbm[(o + 1) * M_] = v1;
    if (lane == ((o + 2) & 63)) outbm[(o + 2) * M_] = v2;
    if (lane == ((o + 3) & 63)) outbm[(o + 3) * M_] = v3;
  }
}

// ---------------------------------------------------------------------------
extern "C" void kernel_launch(void* const* d_in, const int* in_sizes, int n_in,
                              void* d_out, int out_size, void* d_ws, size_t ws_size,
                              hipStream_t stream) {
  const float* xyz = (const float*)d_in[0];
  const float* feat = (const float*)d_in[1];
  const float* w0 = (const float*)d_in[2];
  const float* s0 = (const float*)d_in[3];
  const float* b0 = (const float*)d_in[4];
  const float* w1 = (const float*)d_in[5];
  const float* s1 = (const float*)d_in[6];
  const float* b1 = (const float*)d_in[7];
  const float* w2 = (const float*)d_in[8];
  const float* s2 = (const float*)d_in[9];
  const float* b2 = (const float*)d_in[10];

  float* nxyz = (float*)d_out;                    // [8,3,1024]
  float* out2 = (float*)d_out + B_ * 3 * M_;      // [8,128,1024]

  const size_t nidx_bytes = (size_t)B_ * M_ * K_ * sizeof(int);        // 2 MB
  const size_t ft_bytes = (size_t)B_ * N_ * FTW * sizeof(float);       // ~17.8 MB
  int* nidx = (int*)d_ws;
  float* ft = (float*)((char*)d_ws + nidx_bytes);
  const bool use_ft = ws_size >= nidx_bytes + ft_bytes;

  // FPS (blocks 0-7) fused with ft-table build (blocks 8-63) — independent work.
  hipLaunchKernelGGL(fps_ft_kernel, dim3(use_ft ? 64 : 8), dim3(256), 0, stream,
                     xyz, feat, ft, nxyz);
  hipLaunchKernelGGL(ballq_kernel, dim3(B_ * M_ / 4), dim3(256), 0, stream, xyz, nxyz, nidx);
  if (use_ft) {
    hipLaunchKernelGGL((mlp_kernel<true>), dim3(B_ * M_), dim3(64), 0, stream,
                       ft, xyz, feat, nidx, nxyz, w0, s0, b0, w1, s1, b1, w2, s2, b2, out2);
  } else {
    hipLaunchKernelGGL((mlp_kernel<false>), dim3(B_ * M_), dim3(64), 0, stream,
                       ft, xyz, feat, nidx, nxyz, w0, s0, b0, w1, s1, b1, w2, s2, b2, out2);
  }
}